// Round 6
// baseline (118.762 us; speedup 1.0000x reference)
//
#include <hip/hip_runtime.h>
#include <stdint.h>

// Sampler: temperature -> top-k -> top-p -> softmax -> multinomial (threefry)
// Round-6: pass1 = one 4-deep-unrolled coalesced load burst per thread
// (16 chunks/row, 4096 blocks), collect >=8.0 into LDS, wave0 ballot-select
// local kth, emit {key >= max(kth-4ULP, key(8.0))} with plain stores.
// Tail certifies coverage globally (scaled kth >= 10.01 => raw kth-4ULP >= 8.0)
// and falls back to an exact full-row ballot search if not (never for this data).

#define S_CHUNKS 16
#define PB       256
#define SEG      256
#define TB       64               // tail: one wave per row
#define CAPN     1024
#define SLOTS    (CAPN / TB)      // 16 register key slots per lane
#define WCAP     256
#define TOPP     0.9f
#define TOPT_F   8.0f
#define OK8      0xC1000000u      // orderKey(8.0f)

// Order-preserving float -> uint map (ascending float == ascending uint)
__device__ __forceinline__ unsigned orderKey(float x) {
  unsigned u = __float_as_uint(x);
  return (u & 0x80000000u) ? ~u : (u | 0x80000000u);
}
__device__ __forceinline__ float unorderKey(unsigned k) {
  unsigned u = (k & 0x80000000u) ? (k & 0x7FFFFFFFu) : ~k;
  return __uint_as_float(u);
}

// JAX threefry2x32 (20 rounds), exact.
__device__ __forceinline__ void threefry2x32(unsigned k0, unsigned k1,
                                             unsigned x0, unsigned x1,
                                             unsigned &o0, unsigned &o1) {
  unsigned k2 = k0 ^ k1 ^ 0x1BD11BDAu;
  x0 += k0; x1 += k1;
#define TFR(rr) { x0 += x1; x1 = (x1 << (rr)) | (x1 >> (32 - (rr))); x1 ^= x0; }
  TFR(13) TFR(15) TFR(26) TFR(6)
  x0 += k1; x1 += k2 + 1u;
  TFR(17) TFR(29) TFR(16) TFR(24)
  x0 += k2; x1 += k0 + 2u;
  TFR(13) TFR(15) TFR(26) TFR(6)
  x0 += k0; x1 += k1 + 3u;
  TFR(17) TFR(29) TFR(16) TFR(24)
  x0 += k1; x1 += k2 + 4u;
  TFR(13) TFR(15) TFR(26) TFR(6)
  x0 += k2; x1 += k0 + 5u;
#undef TFR
  o0 = x0; o1 = x1;
}

// ---- Kernel 1: burst-load chunk, collect >=8.0, ballot-select, emit ----
__global__ __launch_bounds__(PB) void k_pass1(
    const float* __restrict__ logits, const int* __restrict__ topk_ptr,
    int* __restrict__ scnt, float* __restrict__ svals, int* __restrict__ sidxs,
    int V) {
  __shared__ float    lval[SEG];
  __shared__ int      lidx[SEG];
  __shared__ unsigned lcnt, ocnt, s_thr;

  const int row = blockIdx.y, chunk = blockIdx.x, tid = threadIdx.x;
  const float* __restrict__ rp = logits + (size_t)row * (size_t)V;
  const float4* __restrict__ rp4 = (const float4*)rp;
  const int V4 = V >> 2;
  const int beg = (int)((long long)chunk * V4 / S_CHUNKS);
  const int end = (int)((long long)(chunk + 1) * V4 / S_CHUNKS);
  const bool last = (chunk == S_CHUNKS - 1);
  const int rembeg = V4 << 2;
  const int sb = row * S_CHUNKS + chunk;

  if (tid == 0) { lcnt = 0u; ocnt = 0u; }
  __syncthreads();

#define PROC(x, idx) do {                                   \
    float _v = (x);                                         \
    if (_v >= TOPT_F) {                                     \
      unsigned _p = atomicAdd(&lcnt, 1u);                   \
      if (_p < SEG) { lval[_p] = _v; lidx[_p] = (idx); }    \
    } } while (0)

  // 4-deep unrolled coalesced burst: all 4 loads issued before any use
  for (int i = beg + tid; i < end; i += 4 * PB) {
    const int e1 = end - 1;
    const int i1 = i + PB, i2 = i + 2 * PB, i3 = i + 3 * PB;
    float4 v0 = rp4[i];
    float4 v1 = rp4[i1 < end ? i1 : e1];
    float4 v2 = rp4[i2 < end ? i2 : e1];
    float4 v3 = rp4[i3 < end ? i3 : e1];
    PROC(v0.x, (i << 2)); PROC(v0.y, (i << 2) + 1);
    PROC(v0.z, (i << 2) + 2); PROC(v0.w, (i << 2) + 3);
    if (i1 < end) {
      PROC(v1.x, (i1 << 2)); PROC(v1.y, (i1 << 2) + 1);
      PROC(v1.z, (i1 << 2) + 2); PROC(v1.w, (i1 << 2) + 3);
    }
    if (i2 < end) {
      PROC(v2.x, (i2 << 2)); PROC(v2.y, (i2 << 2) + 1);
      PROC(v2.z, (i2 << 2) + 2); PROC(v2.w, (i2 << 2) + 3);
    }
    if (i3 < end) {
      PROC(v3.x, (i3 << 2)); PROC(v3.y, (i3 << 2) + 1);
      PROC(v3.z, (i3 << 2) + 2); PROC(v3.w, (i3 << 2) + 3);
    }
  }
  if (last)
    for (int i = rembeg + tid; i < V; i += PB) PROC(rp[i], i);
#undef PROC
  __syncthreads();

  int k = topk_ptr[0];
  if (k < 1) k = 1;
  if (k > V) k = V;
  const int ec = (end - beg) * 4 + (last ? (V - rembeg) : 0);
  const int keff = (k < ec) ? k : ec;

  const unsigned total = lcnt;
  if (total > (unsigned)SEG) {          // buffer overflow (+22 sigma): sentinel
    if (tid == 0) scnt[sb] = -1;
    return;
  }

  if ((int)total >= keff) {
    // wave-0 ballot binary search: exact local keff-th key among buffered
    if (tid < 64) {
      unsigned key[SEG / 64];
#pragma unroll
      for (int t = 0; t < SEG / 64; ++t) {
        int i = tid + t * 64;
        key[t] = (i < (int)total) ? orderKey(lval[i]) : 0u;
      }
      unsigned lo = 1u, hi = 0xFFFFFFFFu;
      while (lo < hi) {
        unsigned mid = lo + ((hi - lo + 1u) >> 1);
        int c = 0;
#pragma unroll
        for (int t = 0; t < SEG / 64; ++t)
          c += __popcll(__ballot(key[t] >= mid));
        if (c >= keff) lo = mid; else hi = mid - 1u;
      }
      if (tid == 0) s_thr = (lo >= OK8 + 4u) ? lo - 4u : OK8;  // 4-ULP margin
    }
  } else {
    if (tid == 0) s_thr = OK8;          // low mode: emit all buffered
  }
  __syncthreads();

  const unsigned thr = s_thr;
  float* __restrict__ ov = svals + (size_t)sb * SEG;
  int*   __restrict__ oi = sidxs + (size_t)sb * SEG;
  for (int i = tid; i < (int)total; i += PB) {
    float x = lval[i];
    if (orderKey(x) >= thr) {
      unsigned pos = atomicAdd(&ocnt, 1u);
      ov[pos] = x;                      // pos < total <= SEG
      oi[pos] = lidx[i];
    }
  }
  __syncthreads();
  if (tid == 0) scnt[sb] = (int)ocnt;
}

// kk-th largest orderKey over sval[0..n), single wave (TB=64), no barriers
__device__ __forceinline__ unsigned kth_key(const float* sval, int n, int kk,
                                            int tid) {
  unsigned key[SLOTS];
#pragma unroll
  for (int t = 0; t < SLOTS; ++t) {
    int i = tid + t * TB;
    key[t] = (i < n) ? orderKey(sval[i]) : 0u;
  }
  unsigned lo = 1u, hi = 0xFFFFFFFFu;
  while (lo < hi) {
    unsigned mid = lo + ((hi - lo + 1u) >> 1);
    int c = 0;
#pragma unroll
    for (int t = 0; t < SLOTS; ++t)
      c += __popcll(__ballot(key[t] >= mid));
    if (c >= kk) lo = mid; else hi = mid - 1u;
  }
  return lo;
}

// ---- Kernel 2: one wave/row — merge, certify, select, sort, sample ----
__global__ __launch_bounds__(TB) void k_tail(
    const float* __restrict__ logits, const int* __restrict__ scnt,
    const float* __restrict__ svals, const int* __restrict__ sidxs,
    const int* __restrict__ topk_ptr, int* __restrict__ out, int V) {
  __shared__ float sval[CAPN];   // scaled candidates
  __shared__ int   sidx[CAPN];
  __shared__ float wv[WCAP];     // survivors (arrival order)
  __shared__ int   wi[WCAP];
  __shared__ float ovv[WCAP];    // sorted survivors
  __shared__ int   oii[WCAP];
  __shared__ float ev[WCAP];
  __shared__ short ord[WCAP];
  __shared__ unsigned s_wc, s_sc;
  __shared__ int   s_K;
  __shared__ float s_S2, s_r;

  const int row = blockIdx.x, tid = threadIdx.x;
  const float* __restrict__ rp = logits + (size_t)row * (size_t)V;
  int k = topk_ptr[0];
  if (k < 1) k = 1;
  if (k > V) k = V;

  if (tid == 0) { s_wc = 0u; s_sc = 0u; }
  __syncthreads();

  // gather segments + temperature scale (IEEE div, matches ref)
  bool slow = false;
  int n = 0;
  {
    int off[S_CHUNKS + 1];
    off[0] = 0;
    for (int c = 0; c < S_CHUNKS; ++c) {
      int cc = scnt[row * S_CHUNKS + c];
      if (cc < 0) { slow = true; cc = 0; }
      off[c + 1] = off[c] + cc;
    }
    n = off[S_CHUNKS];
    if (n > CAPN) slow = true;
    if (!slow) {
      for (int c = 0; c < S_CHUNKS; ++c) {
        const int o = off[c], cn = off[c + 1] - o;
        const float* __restrict__ gv = svals + (size_t)(row * S_CHUNKS + c) * SEG;
        const int*   __restrict__ gi = sidxs + (size_t)(row * S_CHUNKS + c) * SEG;
        for (int i = tid; i < cn; i += TB) {
          sval[o + i] = gv[i] / 0.8f;
          sidx[o + i] = gi[i];
        }
      }
    }
  }
  __syncthreads();

  unsigned kvs = 0u;
  int kk = 0;
  if (!slow && n > 0) {
    kk = (k < n) ? k : n;
    kvs = kth_key(sval, n, kk, tid);
    // certify: scaled kth >= 10.01 => raw kth >= ~8.008 => every chunk's
    // >=8.0 emission covers {raw >= raw_kth - 4ULP}; else exact slow path
    if (unorderKey(kvs) < 10.01f) slow = true;
  }
  if (n == 0 && !slow) { if (tid == 0) out[row] = V; return; }

  if (slow) {
    // exact full-row ballot search on raw keys (never taken for bench data)
    const int kr = (k < V) ? k : V;
    unsigned lo = 1u, hi = 0xFFFFFFFFu;
    while (lo < hi) {
      unsigned mid = lo + ((hi - lo + 1u) >> 1);
      int c = 0;
      for (int i = tid; i < V; i += TB) c += (orderKey(rp[i]) >= mid);
      for (int off = 32; off; off >>= 1) c += __shfl_down(c, off);
      c = __shfl(c, 0);
      if (c >= kr) lo = mid; else hi = mid - 1u;
    }
    const unsigned thr = (lo >= 5u) ? lo - 4u : 1u;
    for (int i = tid; i < V; i += TB) {
      float x = rp[i];
      if (orderKey(x) >= thr) {
        unsigned pos = atomicAdd(&s_sc, 1u);
        if (pos < CAPN) { sval[pos] = x / 0.8f; sidx[pos] = i; }
      }
    }
    __syncthreads();
    n = (int)s_sc;
    if (n > CAPN) n = CAPN;
    kk = (k < n) ? k : n;
    kvs = kth_key(sval, n, kk, tid);
  }

  // survivors = {scaled key >= kvs} == top-k plus ties at the kth scaled value
#pragma unroll
  for (int t = 0; t < SLOTS; ++t) {
    int i = tid + t * TB;
    if (i < n && orderKey(sval[i]) >= kvs) {
      unsigned pos = atomicAdd(&s_wc, 1u);
      if (pos < WCAP) { wv[pos] = sval[i]; wi[pos] = sidx[i]; }
    }
  }
  __syncthreads();
  int ns = (int)s_wc;
  if (ns > WCAP) ns = WCAP;

  // rank-sort survivors: scaled desc, index asc (== ref stable argsort)
  for (int i = tid; i < ns; i += TB) {
    float v = wv[i];
    int   id = wi[i];
    int   rk = 0;
    for (int j = 0; j < ns; ++j) {
      float vj = wv[j];
      rk += (vj > v) || (vj == v && wi[j] < id);
    }
    ovv[rk] = v;
    oii[rk] = id;
  }
  __syncthreads();

  // e = exp(v - max)
  const float mx = ovv[0];
  for (int i = tid; i < ns; i += TB) ev[i] = expf(ovv[i] - mx);
  __syncthreads();

  // top-p keep-prefix + RNG (serial, exact accumulation order)
  if (tid == 0) {
    float S = 0.f;
    for (int i = 0; i < ns; ++i) S += ev[i];
    float c = 0.f;
    int K = ns;
    for (int i = 0; i < ns; ++i) {
      if (i > 0 && c > TOPP) { K = i; break; }  // remove[i] = cdf[i-1] > p
      c += ev[i] / S;
    }
    float S2 = 0.f;
    for (int i = 0; i < K; ++i) S2 += ev[i];
    s_K = K;
    s_S2 = S2;

    // r = uniform from fold_in(key(0), 1), partitionable threefry path
    unsigned kk0, kk1, o0, o1;
    threefry2x32(0u, 0u, 0u, 1u, kk0, kk1);
    threefry2x32(kk0, kk1, 0u, (unsigned)row, o0, o1);
    unsigned bits = o0 ^ o1;
    float r = __uint_as_float((bits >> 9) | 0x3F800000u) - 1.0f;
    s_r = (r < 0.f) ? 0.f : r;
  }
  __syncthreads();
  const int K = s_K;

  // rank kept tokens by original index
  for (int i = tid; i < K; i += TB) {
    int id = oii[i];
    int rk = 0;
    for (int j = 0; j < K; ++j) rk += (oii[j] < id);
    ord[rk] = (short)i;
  }
  __syncthreads();

  // inverse-CDF sample in original-index order
  if (tid == 0) {
    const float S2 = s_S2;
    const float rr = s_r;
    float c = 0.f;
    int ans = V;  // matches sum(cdf <= r) when r beyond total mass
    for (int t = 0; t < K; ++t) {
      int i = ord[t];
      c += ev[i] / S2;
      if (c > rr) { ans = oii[i]; break; }
    }
    out[row] = ans;
  }
}

extern "C" void kernel_launch(void* const* d_in, const int* in_sizes, int n_in,
                              void* d_out, int out_size, void* d_ws, size_t ws_size,
                              hipStream_t stream) {
  const float* logits = (const float*)d_in[0];
  const int*   topk   = (const int*)d_in[1];
  int*         out    = (int*)d_out;
  const int B = out_size;              // 256 rows
  const int V = in_sizes[0] / B;       // 50257

  // workspace layout (no zeroing needed — every slot read is written first)
  char* ws = (char*)d_ws;
  int*   scnt  = (int*)ws;                                           // B*S i32
  float* svals = (float*)(ws + (size_t)B * S_CHUNKS * 4);            // B*S*SEG f32
  int*   sidxs = (int*)(ws + (size_t)B * S_CHUNKS * 4 +
                        (size_t)B * S_CHUNKS * SEG * 4);             // B*S*SEG i32

  hipLaunchKernelGGL(k_pass1, dim3(S_CHUNKS, B), dim3(PB), 0, stream,
                     logits, topk, scnt, svals, sidxs, V);
  hipLaunchKernelGGL(k_tail, dim3(B), dim3(TB), 0, stream,
                     logits, scnt, svals, sidxs, topk, out, V);
}